// Round 3
// baseline (28259.250 us; speedup 1.0000x reference)
//
#include <hip/hip_runtime.h>

#define N_NODES 100000
#define N_EDGES 600000
#define K_DIM   128
#define NPART   ((N_NODES + 255) / 256)   // 391 scan blocks

// ---------------------------------------------------------------- CSR build

__global__ void deg_kernel(const int* __restrict__ dst, int* __restrict__ deg) {
  int e = blockIdx.x * blockDim.x + threadIdx.x;
  if (e < N_EDGES) atomicAdd(&deg[dst[e]], 1);
}

__global__ void scan1_kernel(const int* __restrict__ deg, int* __restrict__ excl,
                             int* __restrict__ partials) {
  __shared__ int s[256];
  int t = threadIdx.x, i = blockIdx.x * 256 + t;
  int v = (i < N_NODES) ? deg[i] : 0;
  s[t] = v;
  __syncthreads();
  for (int off = 1; off < 256; off <<= 1) {
    int x = (t >= off) ? s[t - off] : 0;
    __syncthreads();
    s[t] += x;
    __syncthreads();
  }
  if (i < N_NODES) excl[i] = s[t] - v;
  if (t == 255) partials[blockIdx.x] = s[t];
}

__global__ void scan2_kernel(int* __restrict__ partials) {
  __shared__ int s[512];
  int t = threadIdx.x;
  int v = (t < NPART) ? partials[t] : 0;
  s[t] = v;
  __syncthreads();
  for (int off = 1; off < 512; off <<= 1) {
    int x = (t >= off) ? s[t - off] : 0;
    __syncthreads();
    s[t] += x;
    __syncthreads();
  }
  if (t < NPART) partials[t] = s[t] - v;   // exclusive block offsets
}

__global__ void scan3_kernel(const int* __restrict__ excl, const int* __restrict__ partials,
                             const int* __restrict__ deg, int* __restrict__ row_ptr,
                             int* __restrict__ cursor, float* __restrict__ inv_deg) {
  int i = blockIdx.x * blockDim.x + threadIdx.x;
  if (i < N_NODES) {
    int rp = excl[i] + partials[i >> 8];
    row_ptr[i] = rp;
    cursor[i] = rp;
    inv_deg[i] = 1.0f / (float)(deg[i] > 1 ? deg[i] : 1);
  } else if (i == N_NODES) {
    row_ptr[N_NODES] = N_EDGES;
  }
}

__global__ void fill_kernel(const int* __restrict__ src, const int* __restrict__ dst,
                            int* __restrict__ cursor, int* __restrict__ ssrc) {
  int e = blockIdx.x * blockDim.x + threadIdx.x;
  if (e < N_EDGES) {
    int p = atomicAdd(&cursor[dst[e]], 1);
    ssrc[p] = src[e];
  }
}

// ---------------------------------------------------------------- aggregate
// AGG[v] = inv_deg[v] * sum_{u->v} H[u].  8 lanes per row, 32 rows per block,
// zero LDS, 2-edge unroll for ILP. Latency-bound: occupancy is the lever.

__global__ __launch_bounds__(256, 6) void agg_kernel(
    const float* __restrict__ H, const int* __restrict__ row_ptr,
    const int* __restrict__ ssrc, const float* __restrict__ inv_deg,
    float* __restrict__ AGG) {
  const int tid = threadIdx.x;
  const int cg  = tid & 7;
  const int r   = tid >> 3;
  const int v   = blockIdx.x * 32 + r;
  if (v >= N_NODES) return;

  float a[16];
  #pragma unroll
  for (int i = 0; i < 16; ++i) a[i] = 0.f;

  const int beg = row_ptr[v], end = row_ptr[v + 1];
  int e = beg;
  for (; e + 2 <= end; e += 2) {
    const float* __restrict__ h0 = H + (size_t)ssrc[e] * K_DIM + cg * 4;
    const float* __restrict__ h1 = H + (size_t)ssrc[e + 1] * K_DIM + cg * 4;
    float4 t0[4], t1[4];
    #pragma unroll
    for (int i = 0; i < 4; ++i) t0[i] = *(const float4*)(h0 + i * 32);
    #pragma unroll
    for (int i = 0; i < 4; ++i) t1[i] = *(const float4*)(h1 + i * 32);
    #pragma unroll
    for (int i = 0; i < 4; ++i) {
      a[4 * i + 0] += t0[i].x + t1[i].x;
      a[4 * i + 1] += t0[i].y + t1[i].y;
      a[4 * i + 2] += t0[i].z + t1[i].z;
      a[4 * i + 3] += t0[i].w + t1[i].w;
    }
  }
  if (e < end) {
    const float* __restrict__ h0 = H + (size_t)ssrc[e] * K_DIM + cg * 4;
    #pragma unroll
    for (int i = 0; i < 4; ++i) {
      const float4 t = *(const float4*)(h0 + i * 32);
      a[4 * i + 0] += t.x; a[4 * i + 1] += t.y;
      a[4 * i + 2] += t.z; a[4 * i + 3] += t.w;
    }
  }
  const float sc = inv_deg[v];
  #pragma unroll
  for (int i = 0; i < 4; ++i)
    *(float4*)&AGG[(size_t)v * K_DIM + cg * 4 + i * 32] =
        make_float4(a[4 * i] * sc, a[4 * i + 1] * sc, a[4 * i + 2] * sc, a[4 * i + 3] * sc);
}

// ---------------------------------------------------------------- GEMM
// out = act(A1@W1 [+ A2@W2] + b).  128 rows x DOUT per block, 256 threads,
// thread = 4 rows x DOUT/8 cols. Weights staged in 64-k-row slabs through a
// SINGLE 32/16 KB LDS buffer. No register prefetch, no runtime-indexed
// pointer arrays (round-2 spill lesson: VGPR 84 + 5.7 GB scratch traffic).
// Phase loop fully unrolled so A/W selection is compile-time.
// Alias note: all A reads precede the final __syncthreads(); stores follow it;
// rows are block-partitioned (clamped row N-1 belongs to the last block), so
// `out` may alias A1/A2.

template <int DOUT, bool TWO, bool RELU>
__global__ __launch_bounds__(256, 2) void gemm_kernel(
    const float* __restrict__ A1, const float* __restrict__ A2,
    const float* __restrict__ W1, const float* __restrict__ W2,
    const float* __restrict__ bias, float* __restrict__ out) {
  constexpr int CPT  = DOUT / 8;            // cols per thread: 16 or 8
  constexpr int NI   = CPT / 4;             // float4 groups: 4 or 2
  constexpr int SLAB = 64;                  // k-rows per LDS stage
  constexpr int CF   = SLAB * DOUT;         // floats per slab: 8192 or 4096

  __shared__ float sW[CF];

  const int tid = threadIdx.x;
  const int cg  = tid & 7;
  const int rg  = tid >> 3;
  const int row0 = blockIdx.x * 128 + rg * 4;

  int rowc[4];
  #pragma unroll
  for (int r = 0; r < 4; ++r) {
    int v = row0 + r;
    rowc[r] = v < N_NODES ? v : N_NODES - 1;   // clamp loads; stores guarded
  }

  float acc[4][CPT];
  #pragma unroll
  for (int r = 0; r < 4; ++r)
    #pragma unroll
    for (int c = 0; c < CPT; ++c) acc[r][c] = 0.f;

  #pragma unroll
  for (int ph = 0; ph < (TWO ? 2 : 1); ++ph) {
    const float* __restrict__ A = ph ? A2 : A1;
    const float* __restrict__ W = ph ? W2 : W1;

    #pragma unroll
    for (int kc = 0; kc < K_DIM; kc += SLAB) {
      __syncthreads();   // protect previous slab against overwrite
      #pragma unroll
      for (int i = tid * 4; i < CF; i += 1024)
        *(float4*)&sW[i] = *(const float4*)&W[kc * DOUT + i];
      __syncthreads();

      #pragma unroll
      for (int kk = 0; kk < SLAB; kk += 4) {
        float4 h4[4];
        #pragma unroll
        for (int r = 0; r < 4; ++r)
          h4[r] = *(const float4*)(A + (size_t)rowc[r] * K_DIM + kc + kk);
        #pragma unroll
        for (int kq = 0; kq < 4; ++kq) {
          float4 w4[NI];
          #pragma unroll
          for (int i = 0; i < NI; ++i)
            w4[i] = *(const float4*)&sW[(kk + kq) * DOUT + cg * 4 + i * 32];
          #pragma unroll
          for (int r = 0; r < 4; ++r) {
            const float h = ((const float*)&h4[r])[kq];
            #pragma unroll
            for (int i = 0; i < NI; ++i) {
              acc[r][4 * i + 0] = fmaf(h, w4[i].x, acc[r][4 * i + 0]);
              acc[r][4 * i + 1] = fmaf(h, w4[i].y, acc[r][4 * i + 1]);
              acc[r][4 * i + 2] = fmaf(h, w4[i].z, acc[r][4 * i + 2]);
              acc[r][4 * i + 3] = fmaf(h, w4[i].w, acc[r][4 * i + 3]);
            }
          }
        }
      }
    }
  }
  __syncthreads();

  // epilogue: bias (+ReLU), coalesced float4 stores
  #pragma unroll
  for (int i = 0; i < NI; ++i) {
    const float4 b4 = *(const float4*)&bias[cg * 4 + i * 32];
    #pragma unroll
    for (int r = 0; r < 4; ++r) {
      const int v = row0 + r;
      if (v < N_NODES) {
        float4 o;
        o.x = acc[r][4 * i + 0] + b4.x;
        o.y = acc[r][4 * i + 1] + b4.y;
        o.z = acc[r][4 * i + 2] + b4.z;
        o.w = acc[r][4 * i + 3] + b4.w;
        if (RELU) {
          o.x = o.x > 0.f ? o.x : 0.f;
          o.y = o.y > 0.f ? o.y : 0.f;
          o.z = o.z > 0.f ? o.z : 0.f;
          o.w = o.w > 0.f ? o.w : 0.f;
        }
        *(float4*)&out[(size_t)v * DOUT + cg * 4 + i * 32] = o;
      }
    }
  }
}

// ---------------------------------------------------------------- launcher

extern "C" void kernel_launch(void* const* d_in, const int* in_sizes, int n_in,
                              void* d_out, int out_size, void* d_ws, size_t ws_size,
                              hipStream_t stream) {
  const float* x        = (const float*)d_in[0];
  const int*   src      = (const int*)d_in[1];
  const int*   dst      = (const int*)d_in[2];
  const float* w_self0  = (const float*)d_in[3];
  const float* b_self0  = (const float*)d_in[4];
  const float* w_neigh0 = (const float*)d_in[5];
  const float* fc_w     = (const float*)d_in[6];
  const float* fc_b     = (const float*)d_in[7];
  const float* fc2_w    = (const float*)d_in[8];
  const float* fc2_b    = (const float*)d_in[9];
  const float* w_self1  = (const float*)d_in[10];
  const float* b_self1  = (const float*)d_in[11];
  const float* w_neigh1 = (const float*)d_in[12];
  const float* w_self2  = (const float*)d_in[13];
  const float* b_self2  = (const float*)d_in[14];
  const float* w_neigh2 = (const float*)d_in[15];

  char* p = (char*)d_ws;
  auto carve = [&](size_t bytes) {
    void* q = (void*)p;
    p += (bytes + 511) & ~(size_t)511;
    return q;
  };
  float* F0      = (float*)carve((size_t)N_NODES * K_DIM * 4);
  float* F1      = (float*)carve((size_t)N_NODES * K_DIM * 4);
  int*   ssrc    = (int*)carve((size_t)N_EDGES * 4);
  int*   row_ptr = (int*)carve((size_t)(N_NODES + 1) * 4);
  int*   cursor  = (int*)carve((size_t)N_NODES * 4);
  int*   deg     = (int*)carve((size_t)N_NODES * 4);
  int*   excl    = (int*)carve((size_t)N_NODES * 4);
  int*   parts   = (int*)carve(512 * 4);
  float* inv_deg = (float*)carve((size_t)N_NODES * 4);

  // ---- CSR build (by dst)
  hipMemsetAsync(deg, 0, (size_t)N_NODES * 4, stream);
  const int EB = (N_EDGES + 255) / 256;
  deg_kernel<<<EB, 256, 0, stream>>>(dst, deg);
  scan1_kernel<<<NPART, 256, 0, stream>>>(deg, excl, parts);
  scan2_kernel<<<1, 512, 0, stream>>>(parts);
  scan3_kernel<<<((N_NODES + 1) + 255) / 256, 256, 0, stream>>>(excl, parts, deg,
                                                                row_ptr, cursor, inv_deg);
  fill_kernel<<<EB, 256, 0, stream>>>(src, dst, cursor, ssrc);

  // ---- network
  const int AB = (N_NODES + 31) / 32;     // agg blocks
  const int GB = (N_NODES + 127) / 128;   // gemm blocks

  // layer 0: agg(x)->F0 ; out = relu(x@Ws0 + F0@Wn0 + b) -> F1
  agg_kernel<<<AB, 256, 0, stream>>>(x, row_ptr, ssrc, inv_deg, F0);
  gemm_kernel<128, true, true><<<GB, 256, 0, stream>>>(x, F0, w_self0, w_neigh0,
                                                       b_self0, F1);
  // NGNN inner fc layers
  gemm_kernel<128, false, true><<<GB, 256, 0, stream>>>(F1, nullptr, fc_w, nullptr,
                                                        fc_b, F0);
  gemm_kernel<128, false, true><<<GB, 256, 0, stream>>>(F0, nullptr, fc2_w, nullptr,
                                                        fc2_b, F1);
  // layer 1: agg(F1)->F0 ; out -> F0 (alias with A2 is safe, see kernel comment)
  agg_kernel<<<AB, 256, 0, stream>>>(F1, row_ptr, ssrc, inv_deg, F0);
  gemm_kernel<128, true, true><<<GB, 256, 0, stream>>>(F1, F0, w_self1, w_neigh1,
                                                       b_self1, F0);
  // layer 2: agg(F0)->F1 ; out -> d_out (DOUT=64, no activation)
  agg_kernel<<<AB, 256, 0, stream>>>(F0, row_ptr, ssrc, inv_deg, F1);
  gemm_kernel<64, true, false><<<GB, 256, 0, stream>>>(F0, F1, w_self2, w_neigh2,
                                                       b_self2, (float*)d_out);
}

// Round 4
// 735.148 us; speedup vs baseline: 38.4402x; 38.4402x over previous
//
#include <hip/hip_runtime.h>

#define N_NODES 100000
#define N_EDGES 600000
#define K_DIM   128
#define NPART   ((N_NODES + 255) / 256)   // 391 scan blocks

// ---------------------------------------------------------------- CSR build

__global__ void deg_kernel(const int* __restrict__ dst, int* __restrict__ deg) {
  int e = blockIdx.x * blockDim.x + threadIdx.x;
  if (e < N_EDGES) atomicAdd(&deg[dst[e]], 1);
}

__global__ void scan1_kernel(const int* __restrict__ deg, int* __restrict__ excl,
                             int* __restrict__ partials) {
  __shared__ int s[256];
  int t = threadIdx.x, i = blockIdx.x * 256 + t;
  int v = (i < N_NODES) ? deg[i] : 0;
  s[t] = v;
  __syncthreads();
  for (int off = 1; off < 256; off <<= 1) {
    int x = (t >= off) ? s[t - off] : 0;
    __syncthreads();
    s[t] += x;
    __syncthreads();
  }
  if (i < N_NODES) excl[i] = s[t] - v;
  if (t == 255) partials[blockIdx.x] = s[t];
}

__global__ void scan2_kernel(int* __restrict__ partials) {
  __shared__ int s[512];
  int t = threadIdx.x;
  int v = (t < NPART) ? partials[t] : 0;
  s[t] = v;
  __syncthreads();
  for (int off = 1; off < 512; off <<= 1) {
    int x = (t >= off) ? s[t - off] : 0;
    __syncthreads();
    s[t] += x;
    __syncthreads();
  }
  if (t < NPART) partials[t] = s[t] - v;   // exclusive block offsets
}

__global__ void scan3_kernel(const int* __restrict__ excl, const int* __restrict__ partials,
                             const int* __restrict__ deg, int* __restrict__ row_ptr,
                             int* __restrict__ cursor, float* __restrict__ inv_deg) {
  int i = blockIdx.x * blockDim.x + threadIdx.x;
  if (i < N_NODES) {
    int rp = excl[i] + partials[i >> 8];
    row_ptr[i] = rp;
    cursor[i] = rp;
    inv_deg[i] = 1.0f / (float)(deg[i] > 1 ? deg[i] : 1);
  } else if (i == N_NODES) {
    row_ptr[N_NODES] = N_EDGES;
  }
}

__global__ void fill_kernel(const int* __restrict__ src, const int* __restrict__ dst,
                            int* __restrict__ cursor, int* __restrict__ ssrc) {
  int e = blockIdx.x * blockDim.x + threadIdx.x;
  if (e < N_EDGES) {
    int p = atomicAdd(&cursor[dst[e]], 1);
    ssrc[p] = src[e];
  }
}

// ---------------------------------------------------------------- aggregate
// AGG[v] = inv_deg[v] * sum_{u->v} H[u].  8 lanes per row, 32 rows per block,
// zero LDS, 2-edge unroll for ILP. Latency-bound: occupancy is the lever.

__global__ __launch_bounds__(256, 6) void agg_kernel(
    const float* __restrict__ H, const int* __restrict__ row_ptr,
    const int* __restrict__ ssrc, const float* __restrict__ inv_deg,
    float* __restrict__ AGG) {
  const int tid = threadIdx.x;
  const int cg  = tid & 7;
  const int r   = tid >> 3;
  const int v   = blockIdx.x * 32 + r;
  if (v >= N_NODES) return;

  float a[16];
  #pragma unroll
  for (int i = 0; i < 16; ++i) a[i] = 0.f;

  const int beg = row_ptr[v], end = row_ptr[v + 1];
  int e = beg;
  for (; e + 2 <= end; e += 2) {
    const float* __restrict__ h0 = H + (size_t)ssrc[e] * K_DIM + cg * 4;
    const float* __restrict__ h1 = H + (size_t)ssrc[e + 1] * K_DIM + cg * 4;
    float4 t0[4], t1[4];
    #pragma unroll
    for (int i = 0; i < 4; ++i) t0[i] = *(const float4*)(h0 + i * 32);
    #pragma unroll
    for (int i = 0; i < 4; ++i) t1[i] = *(const float4*)(h1 + i * 32);
    #pragma unroll
    for (int i = 0; i < 4; ++i) {
      a[4 * i + 0] += t0[i].x + t1[i].x;
      a[4 * i + 1] += t0[i].y + t1[i].y;
      a[4 * i + 2] += t0[i].z + t1[i].z;
      a[4 * i + 3] += t0[i].w + t1[i].w;
    }
  }
  if (e < end) {
    const float* __restrict__ h0 = H + (size_t)ssrc[e] * K_DIM + cg * 4;
    #pragma unroll
    for (int i = 0; i < 4; ++i) {
      const float4 t = *(const float4*)(h0 + i * 32);
      a[4 * i + 0] += t.x; a[4 * i + 1] += t.y;
      a[4 * i + 2] += t.z; a[4 * i + 3] += t.w;
    }
  }
  const float sc = inv_deg[v];
  #pragma unroll
  for (int i = 0; i < 4; ++i)
    *(float4*)&AGG[(size_t)v * K_DIM + cg * 4 + i * 32] =
        make_float4(a[4 * i] * sc, a[4 * i + 1] * sc, a[4 * i + 2] * sc, a[4 * i + 3] * sc);
}

// ---------------------------------------------------------------- GEMM
// out = act(A1@W1 [+ A2@W2] + b).  EXACTLY round-1's sage kernel minus the
// gather phase and minus the sAgg LDS buffer: that loop shape is the one this
// compiler allocates cleanly (132 VGPR, zero spills). Rounds 2-3 proved that
// outer-loop unrolling / register prefetch here trigger catastrophic spills
// (WRITE_SIZE 4.5 GB/dispatch) -- do not restructure these loops.
// LDS = one 64/32 KB weight buffer -> 2 blocks/CU (round 1 was 1).
// Alias: each row is read (A-side) only by the 8 lanes that store it, reads
// precede the store; OOB lanes read clamped row N-1 but never store.

template <int DOUT, bool TWO, bool RELU>
__global__ __launch_bounds__(256, 2) void gemm_kernel(
    const float* __restrict__ A1, const float* __restrict__ A2,
    const float* __restrict__ W1, const float* __restrict__ W2,
    const float* __restrict__ bias, float* __restrict__ out) {
  constexpr int CPT = DOUT / 8;   // cols per thread (16 or 8)
  constexpr int NI  = CPT / 4;    // float4 groups (4 or 2)
  __shared__ float sW[K_DIM * DOUT];

  const int tid  = threadIdx.x;
  const int cg   = tid & 7;    // 8 col groups
  const int rg   = tid >> 3;   // 32 row groups
  const int row0 = blockIdx.x * 128;

  // stage W1
  #pragma unroll
  for (int i = tid * 4; i < K_DIM * DOUT; i += 1024)
    *(float4*)&sW[i] = *(const float4*)&W1[i];
  __syncthreads();

  const int r0 = rg * 4;
  float acc[4][CPT];
  #pragma unroll
  for (int r = 0; r < 4; ++r)
    #pragma unroll
    for (int c = 0; c < CPT; ++c) acc[r][c] = 0.f;

  const float* __restrict__ h1base[4];
  const float* __restrict__ h2base[4];
  #pragma unroll
  for (int r = 0; r < 4; ++r) {
    int v = row0 + r0 + r;
    v = v < N_NODES ? v : N_NODES - 1;   // clamp loads; stores guarded
    h1base[r] = A1 + (size_t)v * K_DIM;
    h2base[r] = TWO ? (A2 + (size_t)v * K_DIM) : h1base[r];
  }

  // ---- pass 1: A1 @ W1
  for (int kk = 0; kk < K_DIM; kk += 4) {
    float4 h4[4];
    #pragma unroll
    for (int r = 0; r < 4; ++r) h4[r] = *(const float4*)(h1base[r] + kk);
    #pragma unroll
    for (int kq = 0; kq < 4; ++kq) {
      float4 w4[NI];
      #pragma unroll
      for (int i = 0; i < NI; ++i)
        w4[i] = *(const float4*)&sW[(kk + kq) * DOUT + cg * 4 + i * 32];
      #pragma unroll
      for (int r = 0; r < 4; ++r) {
        const float h = ((const float*)&h4[r])[kq];
        #pragma unroll
        for (int i = 0; i < NI; ++i) {
          acc[r][4 * i + 0] = fmaf(h, w4[i].x, acc[r][4 * i + 0]);
          acc[r][4 * i + 1] = fmaf(h, w4[i].y, acc[r][4 * i + 1]);
          acc[r][4 * i + 2] = fmaf(h, w4[i].z, acc[r][4 * i + 2]);
          acc[r][4 * i + 3] = fmaf(h, w4[i].w, acc[r][4 * i + 3]);
        }
      }
    }
  }

  if (TWO) {
    // ---- swap weights: W2 into the same LDS buffer
    __syncthreads();
    #pragma unroll
    for (int i = tid * 4; i < K_DIM * DOUT; i += 1024)
      *(float4*)&sW[i] = *(const float4*)&W2[i];
    __syncthreads();

    // ---- pass 2: A2 @ W2
    for (int kk = 0; kk < K_DIM; kk += 4) {
      float4 h4[4];
      #pragma unroll
      for (int r = 0; r < 4; ++r) h4[r] = *(const float4*)(h2base[r] + kk);
      #pragma unroll
      for (int kq = 0; kq < 4; ++kq) {
        float4 w4[NI];
        #pragma unroll
        for (int i = 0; i < NI; ++i)
          w4[i] = *(const float4*)&sW[(kk + kq) * DOUT + cg * 4 + i * 32];
        #pragma unroll
        for (int r = 0; r < 4; ++r) {
          const float h = ((const float*)&h4[r])[kq];
          #pragma unroll
          for (int i = 0; i < NI; ++i) {
            acc[r][4 * i + 0] = fmaf(h, w4[i].x, acc[r][4 * i + 0]);
            acc[r][4 * i + 1] = fmaf(h, w4[i].y, acc[r][4 * i + 1]);
            acc[r][4 * i + 2] = fmaf(h, w4[i].z, acc[r][4 * i + 2]);
            acc[r][4 * i + 3] = fmaf(h, w4[i].w, acc[r][4 * i + 3]);
          }
        }
      }
    }
  }

  // ---- epilogue: bias (+ReLU), coalesced float4 stores
  #pragma unroll
  for (int i = 0; i < NI; ++i) {
    const float4 b4 = *(const float4*)&bias[cg * 4 + i * 32];
    #pragma unroll
    for (int r = 0; r < 4; ++r) {
      const int v = row0 + r0 + r;
      if (v < N_NODES) {
        float4 o;
        o.x = acc[r][4 * i + 0] + b4.x;
        o.y = acc[r][4 * i + 1] + b4.y;
        o.z = acc[r][4 * i + 2] + b4.z;
        o.w = acc[r][4 * i + 3] + b4.w;
        if (RELU) {
          o.x = o.x > 0.f ? o.x : 0.f;
          o.y = o.y > 0.f ? o.y : 0.f;
          o.z = o.z > 0.f ? o.z : 0.f;
          o.w = o.w > 0.f ? o.w : 0.f;
        }
        *(float4*)&out[(size_t)v * DOUT + cg * 4 + i * 32] = o;
      }
    }
  }
}

// ---------------------------------------------------------------- launcher

extern "C" void kernel_launch(void* const* d_in, const int* in_sizes, int n_in,
                              void* d_out, int out_size, void* d_ws, size_t ws_size,
                              hipStream_t stream) {
  const float* x        = (const float*)d_in[0];
  const int*   src      = (const int*)d_in[1];
  const int*   dst      = (const int*)d_in[2];
  const float* w_self0  = (const float*)d_in[3];
  const float* b_self0  = (const float*)d_in[4];
  const float* w_neigh0 = (const float*)d_in[5];
  const float* fc_w     = (const float*)d_in[6];
  const float* fc_b     = (const float*)d_in[7];
  const float* fc2_w    = (const float*)d_in[8];
  const float* fc2_b    = (const float*)d_in[9];
  const float* w_self1  = (const float*)d_in[10];
  const float* b_self1  = (const float*)d_in[11];
  const float* w_neigh1 = (const float*)d_in[12];
  const float* w_self2  = (const float*)d_in[13];
  const float* b_self2  = (const float*)d_in[14];
  const float* w_neigh2 = (const float*)d_in[15];

  char* p = (char*)d_ws;
  auto carve = [&](size_t bytes) {
    void* q = (void*)p;
    p += (bytes + 511) & ~(size_t)511;
    return q;
  };
  float* F0      = (float*)carve((size_t)N_NODES * K_DIM * 4);
  float* F1      = (float*)carve((size_t)N_NODES * K_DIM * 4);
  int*   ssrc    = (int*)carve((size_t)N_EDGES * 4);
  int*   row_ptr = (int*)carve((size_t)(N_NODES + 1) * 4);
  int*   cursor  = (int*)carve((size_t)N_NODES * 4);
  int*   deg     = (int*)carve((size_t)N_NODES * 4);
  int*   excl    = (int*)carve((size_t)N_NODES * 4);
  int*   parts   = (int*)carve(512 * 4);
  float* inv_deg = (float*)carve((size_t)N_NODES * 4);

  // ---- CSR build (by dst)
  hipMemsetAsync(deg, 0, (size_t)N_NODES * 4, stream);
  const int EB = (N_EDGES + 255) / 256;
  deg_kernel<<<EB, 256, 0, stream>>>(dst, deg);
  scan1_kernel<<<NPART, 256, 0, stream>>>(deg, excl, parts);
  scan2_kernel<<<1, 512, 0, stream>>>(parts);
  scan3_kernel<<<((N_NODES + 1) + 255) / 256, 256, 0, stream>>>(excl, parts, deg,
                                                                row_ptr, cursor, inv_deg);
  fill_kernel<<<EB, 256, 0, stream>>>(src, dst, cursor, ssrc);

  // ---- network
  const int AB = (N_NODES + 31) / 32;     // agg blocks
  const int GB = (N_NODES + 127) / 128;   // gemm blocks

  // layer 0: agg(x)->F0 ; out = relu(x@Ws0 + F0@Wn0 + b) -> F1
  agg_kernel<<<AB, 256, 0, stream>>>(x, row_ptr, ssrc, inv_deg, F0);
  gemm_kernel<128, true, true><<<GB, 256, 0, stream>>>(x, F0, w_self0, w_neigh0,
                                                       b_self0, F1);
  // NGNN inner fc layers
  gemm_kernel<128, false, true><<<GB, 256, 0, stream>>>(F1, nullptr, fc_w, nullptr,
                                                        fc_b, F0);
  gemm_kernel<128, false, true><<<GB, 256, 0, stream>>>(F0, nullptr, fc2_w, nullptr,
                                                        fc2_b, F1);
  // layer 1: agg(F1)->F0 ; out -> F0 (alias safe, see kernel comment)
  agg_kernel<<<AB, 256, 0, stream>>>(F1, row_ptr, ssrc, inv_deg, F0);
  gemm_kernel<128, true, true><<<GB, 256, 0, stream>>>(F1, F0, w_self1, w_neigh1,
                                                       b_self1, F0);
  // layer 2: agg(F0)->F1 ; out -> d_out (DOUT=64, no activation)
  agg_kernel<<<AB, 256, 0, stream>>>(F0, row_ptr, ssrc, inv_deg, F1);
  gemm_kernel<64, true, false><<<GB, 256, 0, stream>>>(F0, F1, w_self2, w_neigh2,
                                                       b_self2, (float*)d_out);
}

// Round 5
// 546.901 us; speedup vs baseline: 51.6716x; 1.3442x over previous
//
#include <hip/hip_runtime.h>

#define N_NODES 100000
#define N_EDGES 600000
#define K_DIM   128
#define NPART   ((N_NODES + 255) / 256)   // 391 scan blocks

typedef unsigned short ushort_t;
typedef short v8s __attribute__((ext_vector_type(8)));   // 8 bf16 = 4 VGPRs
typedef float v4f __attribute__((ext_vector_type(4)));   // MFMA acc frag

// fp32 -> bf16 round-to-nearest-even (inputs are finite; no NaN handling)
__device__ __forceinline__ ushort_t f2b(float f) {
  unsigned u = __builtin_bit_cast(unsigned, f);
  unsigned r = u + 0x7FFFu + ((u >> 16) & 1u);
  return (ushort_t)(r >> 16);
}
__device__ __forceinline__ float b2f(ushort_t h) {
  return __builtin_bit_cast(float, (unsigned)h << 16);
}
// unpack a uint holding two bf16 (little-endian: element0 = low half)
__device__ __forceinline__ float blo(unsigned u) {
  return __builtin_bit_cast(float, u << 16);
}
__device__ __forceinline__ float bhi(unsigned u) {
  return __builtin_bit_cast(float, u & 0xFFFF0000u);
}

// ---------------------------------------------------------------- CSR build

__global__ void deg_kernel(const int* __restrict__ dst, int* __restrict__ deg) {
  int e = blockIdx.x * blockDim.x + threadIdx.x;
  if (e < N_EDGES) atomicAdd(&deg[dst[e]], 1);
}

__global__ void scan1_kernel(const int* __restrict__ deg, int* __restrict__ excl,
                             int* __restrict__ partials) {
  __shared__ int s[256];
  int t = threadIdx.x, i = blockIdx.x * 256 + t;
  int v = (i < N_NODES) ? deg[i] : 0;
  s[t] = v;
  __syncthreads();
  for (int off = 1; off < 256; off <<= 1) {
    int x = (t >= off) ? s[t - off] : 0;
    __syncthreads();
    s[t] += x;
    __syncthreads();
  }
  if (i < N_NODES) excl[i] = s[t] - v;
  if (t == 255) partials[blockIdx.x] = s[t];
}

__global__ void scan2_kernel(int* __restrict__ partials) {
  __shared__ int s[512];
  int t = threadIdx.x;
  int v = (t < NPART) ? partials[t] : 0;
  s[t] = v;
  __syncthreads();
  for (int off = 1; off < 512; off <<= 1) {
    int x = (t >= off) ? s[t - off] : 0;
    __syncthreads();
    s[t] += x;
    __syncthreads();
  }
  if (t < NPART) partials[t] = s[t] - v;   // exclusive block offsets
}

__global__ void scan3_kernel(const int* __restrict__ excl, const int* __restrict__ partials,
                             const int* __restrict__ deg, int* __restrict__ row_ptr,
                             int* __restrict__ cursor, float* __restrict__ inv_deg) {
  int i = blockIdx.x * blockDim.x + threadIdx.x;
  if (i < N_NODES) {
    int rp = excl[i] + partials[i >> 8];
    row_ptr[i] = rp;
    cursor[i] = rp;
    inv_deg[i] = 1.0f / (float)(deg[i] > 1 ? deg[i] : 1);
  } else if (i == N_NODES) {
    row_ptr[N_NODES] = N_EDGES;
  }
}

__global__ void fill_kernel(const int* __restrict__ src, const int* __restrict__ dst,
                            int* __restrict__ cursor, int* __restrict__ ssrc) {
  int e = blockIdx.x * blockDim.x + threadIdx.x;
  if (e < N_EDGES) {
    int p = atomicAdd(&cursor[dst[e]], 1);
    ssrc[p] = src[e];
  }
}

// ---------------------------------------------------------------- prep

// x (fp32) -> hi/lo bf16 planes: xh = bf16(x), xl = bf16(x - xh)
__global__ void cast_split_kernel(const float* __restrict__ X,
                                  ushort_t* __restrict__ Xh, ushort_t* __restrict__ Xl) {
  int i = (blockIdx.x * 256 + threadIdx.x) * 4;
  if (i >= N_NODES * K_DIM) return;
  float4 v = *(const float4*)(X + i);
  ushort4 h, l;
  h.x = f2b(v.x); l.x = f2b(v.x - b2f(h.x));
  h.y = f2b(v.y); l.y = f2b(v.y - b2f(h.y));
  h.z = f2b(v.z); l.z = f2b(v.z - b2f(h.z));
  h.w = f2b(v.w); l.w = f2b(v.w - b2f(h.w));
  *(ushort4*)(Xh + i) = h;
  *(ushort4*)(Xl + i) = l;
}

// W fp32 [k][n] row-major -> bf16 swizzled to MFMA B-operand layout:
// sw[(k>>3)*DOUT*8 + n*8 + (k&7)] so a lane's 8 k-values for column n are a
// contiguous 16 B run (single ds_read_b128).
template <int DOUT>
__global__ void swizzle_w_kernel(const float* __restrict__ W, ushort_t* __restrict__ Wsw) {
  int t = blockIdx.x * 256 + threadIdx.x;
  if (t >= K_DIM * DOUT) return;
  int k = t / DOUT, n = t % DOUT;
  Wsw[(k >> 3) * (DOUT * 8) + n * 8 + (k & 7)] = f2b(W[t]);
}

// ---------------------------------------------------------------- aggregate
// AGG[v] = inv_deg[v] * sum_{u->v} (hi[u] + lo[u])  (fp32 exact reconstruct),
// re-split into hi/lo planes. 8 lanes/row (16 cols each), 32 rows/block.

__global__ __launch_bounds__(256, 6) void agg_kernel(
    const ushort_t* __restrict__ Hh, const ushort_t* __restrict__ Hl,
    const int* __restrict__ row_ptr, const int* __restrict__ ssrc,
    const float* __restrict__ inv_deg,
    ushort_t* __restrict__ Ah, ushort_t* __restrict__ Al) {
  const int tid = threadIdx.x;
  const int c0  = (tid & 7) * 16;   // 16 columns per lane
  const int r   = tid >> 3;
  const int v   = blockIdx.x * 32 + r;
  if (v >= N_NODES) return;

  float a[16];
  #pragma unroll
  for (int i = 0; i < 16; ++i) a[i] = 0.f;

  const int beg = row_ptr[v], end = row_ptr[v + 1];
  for (int e = beg; e < end; ++e) {
    const size_t ro = (size_t)ssrc[e] * K_DIM + c0;
    const uint4 h0 = *(const uint4*)(Hh + ro);
    const uint4 h1 = *(const uint4*)(Hh + ro + 8);
    const uint4 l0 = *(const uint4*)(Hl + ro);
    const uint4 l1 = *(const uint4*)(Hl + ro + 8);
    a[ 0] += blo(h0.x) + blo(l0.x);  a[ 1] += bhi(h0.x) + bhi(l0.x);
    a[ 2] += blo(h0.y) + blo(l0.y);  a[ 3] += bhi(h0.y) + bhi(l0.y);
    a[ 4] += blo(h0.z) + blo(l0.z);  a[ 5] += bhi(h0.z) + bhi(l0.z);
    a[ 6] += blo(h0.w) + blo(l0.w);  a[ 7] += bhi(h0.w) + bhi(l0.w);
    a[ 8] += blo(h1.x) + blo(l1.x);  a[ 9] += bhi(h1.x) + bhi(l1.x);
    a[10] += blo(h1.y) + blo(l1.y);  a[11] += bhi(h1.y) + bhi(l1.y);
    a[12] += blo(h1.z) + blo(l1.z);  a[13] += bhi(h1.z) + bhi(l1.z);
    a[14] += blo(h1.w) + blo(l1.w);  a[15] += bhi(h1.w) + bhi(l1.w);
  }
  const float sc = inv_deg[v];
  const size_t wo = (size_t)v * K_DIM + c0;
  #pragma unroll
  for (int g = 0; g < 4; ++g) {
    ushort4 oh, ol;
    float x0 = a[4 * g + 0] * sc, x1 = a[4 * g + 1] * sc;
    float x2 = a[4 * g + 2] * sc, x3 = a[4 * g + 3] * sc;
    oh.x = f2b(x0); ol.x = f2b(x0 - b2f(oh.x));
    oh.y = f2b(x1); ol.y = f2b(x1 - b2f(oh.y));
    oh.z = f2b(x2); ol.z = f2b(x2 - b2f(oh.z));
    oh.w = f2b(x3); ol.w = f2b(x3 - b2f(oh.w));
    *(ushort4*)(Ah + wo + 4 * g) = oh;
    *(ushort4*)(Al + wo + 4 * g) = ol;
  }
}

// ---------------------------------------------------------------- MFMA GEMM
// out = act( (A1h+A1l)@W1 [+ (A2h+A2l)@W2] + b ) via 16x16x32 bf16 MFMA,
// split-A compensation: acc = Ah@W + Al@W (W error only ~2^-9 relative).
// Block: 4 waves x 32 rows = 128 rows x DOUT. Wave tile: 2 m-tiles x NT
// n-tiles, acc = 2*NT v4f. A-frags straight from global planes (16 B/lane,
// lane pattern A[m=lane&15][k=quad*8+j]); B-frags from pre-swizzled LDS
// (single ds_read_b128, B[k=quad*8+j][n=lane&15]). ks-loop rolled; keep this
// structure -- rounds 2/3 showed big unrolled regions spill catastrophically.
// Alias: A reads (own rows only) all precede epilogue stores -> out may alias
// A1/A2 planes.

template <int DOUT, bool TWO, bool RELU, bool PLANES_OUT>
__global__ __launch_bounds__(256, 3) void mfma_gemm_kernel(
    const ushort_t* __restrict__ A1h, const ushort_t* __restrict__ A1l,
    const ushort_t* __restrict__ A2h, const ushort_t* __restrict__ A2l,
    const ushort_t* __restrict__ W1sw, const ushort_t* __restrict__ W2sw,
    const float* __restrict__ bias,
    ushort_t* __restrict__ Oh, ushort_t* __restrict__ Ol, float* __restrict__ Ofp) {
  constexpr int NT = DOUT / 16;   // n-tiles per wave: 8 or 4
  __shared__ ushort_t sW[K_DIM * DOUT];

  const int tid  = threadIdx.x;
  const int wv   = tid >> 6;
  const int lane = tid & 63;
  const int lm   = lane & 15;    // m (A) / n (B) index within tile
  const int q    = lane >> 4;    // quad: k-group for A/B, row-group for C
  const int row0 = blockIdx.x * 128 + wv * 32;

  // stage swizzled W1 (32/16 KB)
  for (int i = tid * 16; i < K_DIM * DOUT * 2; i += 4096)
    *(uint4*)((char*)sW + i) = *(const uint4*)((const char*)W1sw + i);
  __syncthreads();

  int ra = row0 + lm;       ra = ra < N_NODES ? ra : N_NODES - 1;
  int rb = row0 + 16 + lm;  rb = rb < N_NODES ? rb : N_NODES - 1;
  const size_t off0 = (size_t)ra * K_DIM;
  const size_t off1 = (size_t)rb * K_DIM;

  v4f acc[2][NT];
  #pragma unroll
  for (int m = 0; m < 2; ++m)
    #pragma unroll
    for (int n = 0; n < NT; ++n) acc[m][n] = (v4f){0.f, 0.f, 0.f, 0.f};

  // ---- phase 1: A1 @ W1
  for (int ks = 0; ks < K_DIM / 32; ++ks) {
    const int ko = ks * 32 + q * 8;
    const v8s a0h = *(const v8s*)(A1h + off0 + ko);
    const v8s a0l = *(const v8s*)(A1l + off0 + ko);
    const v8s a1h = *(const v8s*)(A1h + off1 + ko);
    const v8s a1l = *(const v8s*)(A1l + off1 + ko);
    #pragma unroll
    for (int nt = 0; nt < NT; ++nt) {
      const v8s b = *(const v8s*)&sW[((ks * 4 + q) * DOUT + nt * 16 + lm) * 8];
      acc[0][nt] = __builtin_amdgcn_mfma_f32_16x16x32_bf16(a0h, b, acc[0][nt], 0, 0, 0);
      acc[0][nt] = __builtin_amdgcn_mfma_f32_16x16x32_bf16(a0l, b, acc[0][nt], 0, 0, 0);
      acc[1][nt] = __builtin_amdgcn_mfma_f32_16x16x32_bf16(a1h, b, acc[1][nt], 0, 0, 0);
      acc[1][nt] = __builtin_amdgcn_mfma_f32_16x16x32_bf16(a1l, b, acc[1][nt], 0, 0, 0);
    }
  }

  if (TWO) {
    __syncthreads();
    for (int i = tid * 16; i < K_DIM * DOUT * 2; i += 4096)
      *(uint4*)((char*)sW + i) = *(const uint4*)((const char*)W2sw + i);
    __syncthreads();

    // ---- phase 2: A2 @ W2
    for (int ks = 0; ks < K_DIM / 32; ++ks) {
      const int ko = ks * 32 + q * 8;
      const v8s a0h = *(const v8s*)(A2h + off0 + ko);
      const v8s a0l = *(const v8s*)(A2l + off0 + ko);
      const v8s a1h = *(const v8s*)(A2h + off1 + ko);
      const v8s a1l = *(const v8s*)(A2l + off1 + ko);
      #pragma unroll
      for (int nt = 0; nt < NT; ++nt) {
        const v8s b = *(const v8s*)&sW[((ks * 4 + q) * DOUT + nt * 16 + lm) * 8];
        acc[0][nt] = __builtin_amdgcn_mfma_f32_16x16x32_bf16(a0h, b, acc[0][nt], 0, 0, 0);
        acc[0][nt] = __builtin_amdgcn_mfma_f32_16x16x32_bf16(a0l, b, acc[0][nt], 0, 0, 0);
        acc[1][nt] = __builtin_amdgcn_mfma_f32_16x16x32_bf16(a1h, b, acc[1][nt], 0, 0, 0);
        acc[1][nt] = __builtin_amdgcn_mfma_f32_16x16x32_bf16(a1l, b, acc[1][nt], 0, 0, 0);
      }
    }
  }

  // ---- epilogue: C/D layout col=lane&15, row=quad*4+reg
  #pragma unroll
  for (int m = 0; m < 2; ++m) {
    #pragma unroll
    for (int nt = 0; nt < NT; ++nt) {
      const int col = nt * 16 + lm;
      const float bv = bias[col];
      #pragma unroll
      for (int r = 0; r < 4; ++r) {
        const int row = row0 + m * 16 + q * 4 + r;
        if (row < N_NODES) {
          float v = acc[m][nt][r] + bv;
          if (RELU) v = v > 0.f ? v : 0.f;
          if (PLANES_OUT) {
            const ushort_t h = f2b(v);
            Oh[(size_t)row * DOUT + col] = h;
            Ol[(size_t)row * DOUT + col] = f2b(v - b2f(h));
          } else {
            Ofp[(size_t)row * DOUT + col] = v;
          }
        }
      }
    }
  }
}

// ---------------------------------------------------------------- launcher

extern "C" void kernel_launch(void* const* d_in, const int* in_sizes, int n_in,
                              void* d_out, int out_size, void* d_ws, size_t ws_size,
                              hipStream_t stream) {
  const float* x        = (const float*)d_in[0];
  const int*   src      = (const int*)d_in[1];
  const int*   dst      = (const int*)d_in[2];
  const float* w_self0  = (const float*)d_in[3];
  const float* b_self0  = (const float*)d_in[4];
  const float* w_neigh0 = (const float*)d_in[5];
  const float* fc_w     = (const float*)d_in[6];
  const float* fc_b     = (const float*)d_in[7];
  const float* fc2_w    = (const float*)d_in[8];
  const float* fc2_b    = (const float*)d_in[9];
  const float* w_self1  = (const float*)d_in[10];
  const float* b_self1  = (const float*)d_in[11];
  const float* w_neigh1 = (const float*)d_in[12];
  const float* w_self2  = (const float*)d_in[13];
  const float* b_self2  = (const float*)d_in[14];
  const float* w_neigh2 = (const float*)d_in[15];

  char* p = (char*)d_ws;
  auto carve = [&](size_t bytes) {
    void* q = (void*)p;
    p += (bytes + 511) & ~(size_t)511;
    return q;
  };
  const size_t PLANE = (size_t)N_NODES * K_DIM * sizeof(ushort_t);   // 25.6 MB
  ushort_t* Xh  = (ushort_t*)carve(PLANE);
  ushort_t* Xl  = (ushort_t*)carve(PLANE);
  ushort_t* B1h = (ushort_t*)carve(PLANE);
  ushort_t* B1l = (ushort_t*)carve(PLANE);
  ushort_t* ws0 = (ushort_t*)carve(K_DIM * 128 * 2);
  ushort_t* wn0 = (ushort_t*)carve(K_DIM * 128 * 2);
  ushort_t* wfc = (ushort_t*)carve(K_DIM * 128 * 2);
  ushort_t* wf2 = (ushort_t*)carve(K_DIM * 128 * 2);
  ushort_t* ws1 = (ushort_t*)carve(K_DIM * 128 * 2);
  ushort_t* wn1 = (ushort_t*)carve(K_DIM * 128 * 2);
  ushort_t* ws2 = (ushort_t*)carve(K_DIM * 64 * 2);
  ushort_t* wn2 = (ushort_t*)carve(K_DIM * 64 * 2);
  int*   ssrc    = (int*)carve((size_t)N_EDGES * 4);
  int*   row_ptr = (int*)carve((size_t)(N_NODES + 1) * 4);
  int*   cursor  = (int*)carve((size_t)N_NODES * 4);
  int*   deg     = (int*)carve((size_t)N_NODES * 4);
  int*   excl    = (int*)carve((size_t)N_NODES * 4);
  int*   parts   = (int*)carve(512 * 4);
  float* inv_deg = (float*)carve((size_t)N_NODES * 4);

  // ---- CSR build (by dst)
  hipMemsetAsync(deg, 0, (size_t)N_NODES * 4, stream);
  const int EB = (N_EDGES + 255) / 256;
  deg_kernel<<<EB, 256, 0, stream>>>(dst, deg);
  scan1_kernel<<<NPART, 256, 0, stream>>>(deg, excl, parts);
  scan2_kernel<<<1, 512, 0, stream>>>(parts);
  scan3_kernel<<<((N_NODES + 1) + 255) / 256, 256, 0, stream>>>(excl, parts, deg,
                                                                row_ptr, cursor, inv_deg);
  fill_kernel<<<EB, 256, 0, stream>>>(src, dst, cursor, ssrc);

  // ---- prep: split x, swizzle weights to bf16 B-operand layout
  cast_split_kernel<<<(N_NODES * K_DIM / 4 + 255) / 256, 256, 0, stream>>>(x, Xh, Xl);
  swizzle_w_kernel<128><<<64, 256, 0, stream>>>(w_self0, ws0);
  swizzle_w_kernel<128><<<64, 256, 0, stream>>>(w_neigh0, wn0);
  swizzle_w_kernel<128><<<64, 256, 0, stream>>>(fc_w, wfc);
  swizzle_w_kernel<128><<<64, 256, 0, stream>>>(fc2_w, wf2);
  swizzle_w_kernel<128><<<64, 256, 0, stream>>>(w_self1, ws1);
  swizzle_w_kernel<128><<<64, 256, 0, stream>>>(w_neigh1, wn1);
  swizzle_w_kernel<64><<<32, 256, 0, stream>>>(w_self2, ws2);
  swizzle_w_kernel<64><<<32, 256, 0, stream>>>(w_neigh2, wn2);

  // ---- network (plane ping-pong: X pair + B1 pair)
  const int AB = (N_NODES + 31) / 32;
  const int GB = (N_NODES + 127) / 128;

  // layer 0: agg(X)->B1 ; relu(X@Ws0 + B1@Wn0 + b) -> B1 (alias-safe)
  agg_kernel<<<AB, 256, 0, stream>>>(Xh, Xl, row_ptr, ssrc, inv_deg, B1h, B1l);
  mfma_gemm_kernel<128, true, true, true><<<GB, 256, 0, stream>>>(
      Xh, Xl, B1h, B1l, ws0, wn0, b_self0, B1h, B1l, nullptr);
  // NGNN fc layers: B1 -> X -> B1
  mfma_gemm_kernel<128, false, true, true><<<GB, 256, 0, stream>>>(
      B1h, B1l, B1h, B1l, wfc, wfc, fc_b, Xh, Xl, nullptr);
  mfma_gemm_kernel<128, false, true, true><<<GB, 256, 0, stream>>>(
      Xh, Xl, Xh, Xl, wf2, wf2, fc2_b, B1h, B1l, nullptr);
  // layer 1: agg(B1)->X ; relu(B1@Ws1 + X@Wn1 + b) -> B1
  agg_kernel<<<AB, 256, 0, stream>>>(B1h, B1l, row_ptr, ssrc, inv_deg, Xh, Xl);
  mfma_gemm_kernel<128, true, true, true><<<GB, 256, 0, stream>>>(
      B1h, B1l, Xh, Xl, ws1, wn1, b_self1, B1h, B1l, nullptr);
  // layer 2: agg(B1)->X ; B1@Ws2 + X@Wn2 + b -> d_out (fp32, DOUT=64)
  agg_kernel<<<AB, 256, 0, stream>>>(B1h, B1l, row_ptr, ssrc, inv_deg, Xh, Xl);
  mfma_gemm_kernel<64, true, false, false><<<GB, 256, 0, stream>>>(
      B1h, B1l, Xh, Xl, ws2, wn2, b_self2, nullptr, nullptr, (float*)d_out);
}

// Round 6
// 467.776 us; speedup vs baseline: 60.4120x; 1.1692x over previous
//
#include <hip/hip_runtime.h>

#define N_NODES 100000
#define N_EDGES 600000
#define K_DIM   128
#define NPART   ((N_NODES + 255) / 256)   // 391 scan blocks

typedef unsigned short ushort_t;
typedef short v8s __attribute__((ext_vector_type(8)));   // 8 bf16 = 4 VGPRs
typedef float v4f __attribute__((ext_vector_type(4)));   // MFMA acc frag

// fp32 -> bf16 round-to-nearest-even (inputs are finite; no NaN handling)
__device__ __forceinline__ ushort_t f2b(float f) {
  unsigned u = __builtin_bit_cast(unsigned, f);
  unsigned r = u + 0x7FFFu + ((u >> 16) & 1u);
  return (ushort_t)(r >> 16);
}
__device__ __forceinline__ float b2f(ushort_t h) {
  return __builtin_bit_cast(float, (unsigned)h << 16);
}
// unpack a uint holding two bf16 (little-endian: element0 = low half)
__device__ __forceinline__ float blo(unsigned u) {
  return __builtin_bit_cast(float, u << 16);
}
__device__ __forceinline__ float bhi(unsigned u) {
  return __builtin_bit_cast(float, u & 0xFFFF0000u);
}

// ---------------------------------------------------------------- CSR build

__global__ void deg_kernel(const int* __restrict__ dst, int* __restrict__ deg) {
  int e = blockIdx.x * blockDim.x + threadIdx.x;
  if (e < N_EDGES) atomicAdd(&deg[dst[e]], 1);
}

__global__ void scan1_kernel(const int* __restrict__ deg, int* __restrict__ excl,
                             int* __restrict__ partials) {
  __shared__ int s[256];
  int t = threadIdx.x, i = blockIdx.x * 256 + t;
  int v = (i < N_NODES) ? deg[i] : 0;
  s[t] = v;
  __syncthreads();
  for (int off = 1; off < 256; off <<= 1) {
    int x = (t >= off) ? s[t - off] : 0;
    __syncthreads();
    s[t] += x;
    __syncthreads();
  }
  if (i < N_NODES) excl[i] = s[t] - v;
  if (t == 255) partials[blockIdx.x] = s[t];
}

__global__ void scan2_kernel(int* __restrict__ partials) {
  __shared__ int s[512];
  int t = threadIdx.x;
  int v = (t < NPART) ? partials[t] : 0;
  s[t] = v;
  __syncthreads();
  for (int off = 1; off < 512; off <<= 1) {
    int x = (t >= off) ? s[t - off] : 0;
    __syncthreads();
    s[t] += x;
    __syncthreads();
  }
  if (t < NPART) partials[t] = s[t] - v;   // exclusive block offsets
}

__global__ void scan3_kernel(const int* __restrict__ excl, const int* __restrict__ partials,
                             const int* __restrict__ deg, int* __restrict__ row_ptr,
                             int* __restrict__ cursor, float* __restrict__ inv_deg) {
  int i = blockIdx.x * blockDim.x + threadIdx.x;
  if (i < N_NODES) {
    int rp = excl[i] + partials[i >> 8];
    row_ptr[i] = rp;
    cursor[i] = rp;
    inv_deg[i] = 1.0f / (float)(deg[i] > 1 ? deg[i] : 1);
  } else if (i == N_NODES) {
    row_ptr[N_NODES] = N_EDGES;
  }
}

__global__ void fill_kernel(const int* __restrict__ src, const int* __restrict__ dst,
                            int* __restrict__ cursor, int* __restrict__ ssrc) {
  int e = blockIdx.x * blockDim.x + threadIdx.x;
  if (e < N_EDGES) {
    int p = atomicAdd(&cursor[dst[e]], 1);
    ssrc[p] = src[e];
  }
}

// ---------------------------------------------------------------- prep

// x (fp32) -> hi/lo bf16 planes: xh = bf16(x), xl = bf16(x - xh)
__global__ void cast_split_kernel(const float* __restrict__ X,
                                  ushort_t* __restrict__ Xh, ushort_t* __restrict__ Xl) {
  int i = (blockIdx.x * 256 + threadIdx.x) * 4;
  if (i >= N_NODES * K_DIM) return;
  float4 v = *(const float4*)(X + i);
  ushort4 h, l;
  h.x = f2b(v.x); l.x = f2b(v.x - b2f(h.x));
  h.y = f2b(v.y); l.y = f2b(v.y - b2f(h.y));
  h.z = f2b(v.z); l.z = f2b(v.z - b2f(h.z));
  h.w = f2b(v.w); l.w = f2b(v.w - b2f(h.w));
  *(ushort4*)(Xh + i) = h;
  *(ushort4*)(Xl + i) = l;
}

// All 8 weights swizzled in ONE launch (blockIdx.z selects the weight).
// Layout: sw[(k>>3)*DOUT*8 + n*8 + (k&7)] -> lane's 8 k-values contiguous.
__global__ void swizzle_all_kernel(
    const float* __restrict__ w0, const float* __restrict__ w1,
    const float* __restrict__ w2, const float* __restrict__ w3,
    const float* __restrict__ w4, const float* __restrict__ w5,
    const float* __restrict__ w6, const float* __restrict__ w7,
    ushort_t* __restrict__ s0, ushort_t* __restrict__ s1,
    ushort_t* __restrict__ s2, ushort_t* __restrict__ s3,
    ushort_t* __restrict__ s4, ushort_t* __restrict__ s5,
    ushort_t* __restrict__ s6, ushort_t* __restrict__ s7) {
  const int z = blockIdx.z;
  const float* W;
  ushort_t* S;
  int dout = 128;
  switch (z) {
    case 0: W = w0; S = s0; break;
    case 1: W = w1; S = s1; break;
    case 2: W = w2; S = s2; break;
    case 3: W = w3; S = s3; break;
    case 4: W = w4; S = s4; break;
    case 5: W = w5; S = s5; break;
    case 6: W = w6; S = s6; dout = 64; break;
    default: W = w7; S = s7; dout = 64; break;
  }
  int t = blockIdx.x * 256 + threadIdx.x;
  if (t >= K_DIM * dout) return;
  int k = t / dout, n = t % dout;
  S[(k >> 3) * (dout * 8) + n * 8 + (k & 7)] = f2b(W[t]);
}

// ---------------------------------------------------------------- aggregate
// AGG[v] = inv_deg[v] * sum_{u->v} Hh[u]   (hi plane only: the extra bf16
// input rounding (~2^-9 rel) is the same magnitude as the W rounding already
// in the error budget -- halves the random-read bytes). Result re-split into
// hi/lo planes. 8 lanes/row (16 cols each), 32 rows/block, 2-edge unroll for
// MLP (4 uint4 loads in flight), max-occupancy launch bounds.

__global__ __launch_bounds__(256, 8) void agg_kernel(
    const ushort_t* __restrict__ Hh,
    const int* __restrict__ row_ptr, const int* __restrict__ ssrc,
    const float* __restrict__ inv_deg,
    ushort_t* __restrict__ Ah, ushort_t* __restrict__ Al) {
  const int tid = threadIdx.x;
  const int c0  = (tid & 7) * 16;   // 16 columns per lane
  const int r   = tid >> 3;
  const int v   = blockIdx.x * 32 + r;
  if (v >= N_NODES) return;

  float a[16];
  #pragma unroll
  for (int i = 0; i < 16; ++i) a[i] = 0.f;

  const int beg = row_ptr[v], end = row_ptr[v + 1];
  int e = beg;
  for (; e + 2 <= end; e += 2) {
    const size_t r0 = (size_t)ssrc[e] * K_DIM + c0;
    const size_t r1 = (size_t)ssrc[e + 1] * K_DIM + c0;
    const uint4 p0 = *(const uint4*)(Hh + r0);
    const uint4 p1 = *(const uint4*)(Hh + r0 + 8);
    const uint4 q0 = *(const uint4*)(Hh + r1);
    const uint4 q1 = *(const uint4*)(Hh + r1 + 8);
    a[ 0] += blo(p0.x) + blo(q0.x);  a[ 1] += bhi(p0.x) + bhi(q0.x);
    a[ 2] += blo(p0.y) + blo(q0.y);  a[ 3] += bhi(p0.y) + bhi(q0.y);
    a[ 4] += blo(p0.z) + blo(q0.z);  a[ 5] += bhi(p0.z) + bhi(q0.z);
    a[ 6] += blo(p0.w) + blo(q0.w);  a[ 7] += bhi(p0.w) + bhi(q0.w);
    a[ 8] += blo(p1.x) + blo(q1.x);  a[ 9] += bhi(p1.x) + bhi(q1.x);
    a[10] += blo(p1.y) + blo(q1.y);  a[11] += bhi(p1.y) + bhi(q1.y);
    a[12] += blo(p1.z) + blo(q1.z);  a[13] += bhi(p1.z) + bhi(q1.z);
    a[14] += blo(p1.w) + blo(q1.w);  a[15] += bhi(p1.w) + bhi(q1.w);
  }
  if (e < end) {
    const size_t r0 = (size_t)ssrc[e] * K_DIM + c0;
    const uint4 p0 = *(const uint4*)(Hh + r0);
    const uint4 p1 = *(const uint4*)(Hh + r0 + 8);
    a[ 0] += blo(p0.x);  a[ 1] += bhi(p0.x);
    a[ 2] += blo(p0.y);  a[ 3] += bhi(p0.y);
    a[ 4] += blo(p0.z);  a[ 5] += bhi(p0.z);
    a[ 6] += blo(p0.w);  a[ 7] += bhi(p0.w);
    a[ 8] += blo(p1.x);  a[ 9] += bhi(p1.x);
    a[10] += blo(p1.y);  a[11] += bhi(p1.y);
    a[12] += blo(p1.z);  a[13] += bhi(p1.z);
    a[14] += blo(p1.w);  a[15] += bhi(p1.w);
  }
  const float sc = inv_deg[v];
  const size_t wo = (size_t)v * K_DIM + c0;
  #pragma unroll
  for (int g = 0; g < 4; ++g) {
    ushort4 oh, ol;
    float x0 = a[4 * g + 0] * sc, x1 = a[4 * g + 1] * sc;
    float x2 = a[4 * g + 2] * sc, x3 = a[4 * g + 3] * sc;
    oh.x = f2b(x0); ol.x = f2b(x0 - b2f(oh.x));
    oh.y = f2b(x1); ol.y = f2b(x1 - b2f(oh.y));
    oh.z = f2b(x2); ol.z = f2b(x2 - b2f(oh.z));
    oh.w = f2b(x3); ol.w = f2b(x3 - b2f(oh.w));
    *(ushort4*)(Ah + wo + 4 * g) = oh;
    *(ushort4*)(Al + wo + 4 * g) = ol;
  }
}

// ---------------------------------------------------------------- MFMA GEMM
// out = act( (A1h+A1l)@W1 [+ (A2h+A2l)@W2] + b ) via 16x16x32 bf16 MFMA,
// split-A compensation: acc = Ah@W + Al@W (W error only ~2^-9 relative).
// Block: 4 waves x 32 rows = 128 rows x DOUT. Wave tile: 2 m-tiles x NT
// n-tiles, acc = 2*NT v4f. A-frags straight from global planes (16 B/lane,
// lane pattern A[m=lane&15][k=quad*8+j]); B-frags from pre-swizzled LDS
// (single ds_read_b128, B[k=quad*8+j][n=lane&15]). ks-loop rolled; keep this
// structure -- rounds 2/3 showed big unrolled regions spill catastrophically.
// Alias: A reads (own rows only) all precede epilogue stores -> out may alias
// A1/A2 planes.  DO NOT restructure these loops (spill tripwire: WRITE_SIZE
// >> output size).

template <int DOUT, bool TWO, bool RELU, bool PLANES_OUT>
__global__ __launch_bounds__(256, 3) void mfma_gemm_kernel(
    const ushort_t* __restrict__ A1h, const ushort_t* __restrict__ A1l,
    const ushort_t* __restrict__ A2h, const ushort_t* __restrict__ A2l,
    const ushort_t* __restrict__ W1sw, const ushort_t* __restrict__ W2sw,
    const float* __restrict__ bias,
    ushort_t* __restrict__ Oh, ushort_t* __restrict__ Ol, float* __restrict__ Ofp) {
  constexpr int NT = DOUT / 16;   // n-tiles per wave: 8 or 4
  __shared__ ushort_t sW[K_DIM * DOUT];

  const int tid  = threadIdx.x;
  const int wv   = tid >> 6;
  const int lane = tid & 63;
  const int lm   = lane & 15;    // m (A) / n (B) index within tile
  const int q    = lane >> 4;    // quad: k-group for A/B, row-group for C
  const int row0 = blockIdx.x * 128 + wv * 32;

  // stage swizzled W1 (32/16 KB)
  for (int i = tid * 16; i < K_DIM * DOUT * 2; i += 4096)
    *(uint4*)((char*)sW + i) = *(const uint4*)((const char*)W1sw + i);
  __syncthreads();

  int ra = row0 + lm;       ra = ra < N_NODES ? ra : N_NODES - 1;
  int rb = row0 + 16 + lm;  rb = rb < N_NODES ? rb : N_NODES - 1;
  const size_t off0 = (size_t)ra * K_DIM;
  const size_t off1 = (size_t)rb * K_DIM;

  v4f acc[2][NT];
  #pragma unroll
  for (int m = 0; m < 2; ++m)
    #pragma unroll
    for (int n = 0; n < NT; ++n) acc[m][n] = (v4f){0.f, 0.f, 0.f, 0.f};

  // ---- phase 1: A1 @ W1
  for (int ks = 0; ks < K_DIM / 32; ++ks) {
    const int ko = ks * 32 + q * 8;
    const v8s a0h = *(const v8s*)(A1h + off0 + ko);
    const v8s a0l = *(const v8s*)(A1l + off0 + ko);
    const v8s a1h = *(const v8s*)(A1h + off1 + ko);
    const v8s a1l = *(const v8s*)(A1l + off1 + ko);
    #pragma unroll
    for (int nt = 0; nt < NT; ++nt) {
      const v8s b = *(const v8s*)&sW[((ks * 4 + q) * DOUT + nt * 16 + lm) * 8];
      acc[0][nt] = __builtin_amdgcn_mfma_f32_16x16x32_bf16(a0h, b, acc[0][nt], 0, 0, 0);
      acc[0][nt] = __builtin_amdgcn_mfma_f32_16x16x32_bf16(a0l, b, acc[0][nt], 0, 0, 0);
      acc[1][nt] = __builtin_amdgcn_mfma_f32_16x16x32_bf16(a1h, b, acc[1][nt], 0, 0, 0);
      acc[1][nt] = __builtin_amdgcn_mfma_f32_16x16x32_bf16(a1l, b, acc[1][nt], 0, 0, 0);
    }
  }

  if (TWO) {
    __syncthreads();
    for (int i = tid * 16; i < K_DIM * DOUT * 2; i += 4096)
      *(uint4*)((char*)sW + i) = *(const uint4*)((const char*)W2sw + i);
    __syncthreads();

    // ---- phase 2: A2 @ W2
    for (int ks = 0; ks < K_DIM / 32; ++ks) {
      const int ko = ks * 32 + q * 8;
      const v8s a0h = *(const v8s*)(A2h + off0 + ko);
      const v8s a0l = *(const v8s*)(A2l + off0 + ko);
      const v8s a1h = *(const v8s*)(A2h + off1 + ko);
      const v8s a1l = *(const v8s*)(A2l + off1 + ko);
      #pragma unroll
      for (int nt = 0; nt < NT; ++nt) {
        const v8s b = *(const v8s*)&sW[((ks * 4 + q) * DOUT + nt * 16 + lm) * 8];
        acc[0][nt] = __builtin_amdgcn_mfma_f32_16x16x32_bf16(a0h, b, acc[0][nt], 0, 0, 0);
        acc[0][nt] = __builtin_amdgcn_mfma_f32_16x16x32_bf16(a0l, b, acc[0][nt], 0, 0, 0);
        acc[1][nt] = __builtin_amdgcn_mfma_f32_16x16x32_bf16(a1h, b, acc[1][nt], 0, 0, 0);
        acc[1][nt] = __builtin_amdgcn_mfma_f32_16x16x32_bf16(a1l, b, acc[1][nt], 0, 0, 0);
      }
    }
  }

  // ---- epilogue: C/D layout col=lane&15, row=quad*4+reg
  #pragma unroll
  for (int m = 0; m < 2; ++m) {
    #pragma unroll
    for (int nt = 0; nt < NT; ++nt) {
      const int col = nt * 16 + lm;
      const float bv = bias[col];
      #pragma unroll
      for (int r = 0; r < 4; ++r) {
        const int row = row0 + m * 16 + q * 4 + r;
        if (row < N_NODES) {
          float v = acc[m][nt][r] + bv;
          if (RELU) v = v > 0.f ? v : 0.f;
          if (PLANES_OUT) {
            const ushort_t h = f2b(v);
            Oh[(size_t)row * DOUT + col] = h;
            Ol[(size_t)row * DOUT + col] = f2b(v - b2f(h));
          } else {
            Ofp[(size_t)row * DOUT + col] = v;
          }
        }
      }
    }
  }
}

// ---------------------------------------------------------------- launcher

extern "C" void kernel_launch(void* const* d_in, const int* in_sizes, int n_in,
                              void* d_out, int out_size, void* d_ws, size_t ws_size,
                              hipStream_t stream) {
  const float* x        = (const float*)d_in[0];
  const int*   src      = (const int*)d_in[1];
  const int*   dst      = (const int*)d_in[2];
  const float* w_self0  = (const float*)d_in[3];
  const float* b_self0  = (const float*)d_in[4];
  const float* w_neigh0 = (const float*)d_in[5];
  const float* fc_w     = (const float*)d_in[6];
  const float* fc_b     = (const float*)d_in[7];
  const float* fc2_w    = (const float*)d_in[8];
  const float* fc2_b    = (const float*)d_in[9];
  const float* w_self1  = (const float*)d_in[10];
  const float* b_self1  = (const float*)d_in[11];
  const float* w_neigh1 = (const float*)d_in[12];
  const float* w_self2  = (const float*)d_in[13];
  const float* b_self2  = (const float*)d_in[14];
  const float* w_neigh2 = (const float*)d_in[15];

  char* p = (char*)d_ws;
  auto carve = [&](size_t bytes) {
    void* q = (void*)p;
    p += (bytes + 511) & ~(size_t)511;
    return q;
  };
  const size_t PLANE = (size_t)N_NODES * K_DIM * sizeof(ushort_t);   // 25.6 MB
  ushort_t* Xh  = (ushort_t*)carve(PLANE);
  ushort_t* Xl  = (ushort_t*)carve(PLANE);
  ushort_t* B1h = (ushort_t*)carve(PLANE);
  ushort_t* B1l = (ushort_t*)carve(PLANE);
  ushort_t* ws0 = (ushort_t*)carve(K_DIM * 128 * 2);
  ushort_t* wn0 = (ushort_t*)carve(K_DIM * 128 * 2);
  ushort_t* wfc = (ushort_t*)carve(K_DIM * 128 * 2);
  ushort_t* wf2 = (ushort_t*)carve(K_DIM * 128 * 2);
  ushort_t* ws1 = (ushort_t*)carve(K_DIM * 128 * 2);
  ushort_t* wn1 = (ushort_t*)carve(K_DIM * 128 * 2);
  ushort_t* ws2 = (ushort_t*)carve(K_DIM * 64 * 2);
  ushort_t* wn2 = (ushort_t*)carve(K_DIM * 64 * 2);
  int*   ssrc    = (int*)carve((size_t)N_EDGES * 4);
  int*   row_ptr = (int*)carve((size_t)(N_NODES + 1) * 4);
  int*   cursor  = (int*)carve((size_t)N_NODES * 4);
  int*   deg     = (int*)carve((size_t)N_NODES * 4);
  int*   excl    = (int*)carve((size_t)N_NODES * 4);
  int*   parts   = (int*)carve(512 * 4);
  float* inv_deg = (float*)carve((size_t)N_NODES * 4);

  // ---- CSR build (by dst)
  hipMemsetAsync(deg, 0, (size_t)N_NODES * 4, stream);
  const int EB = (N_EDGES + 255) / 256;
  deg_kernel<<<EB, 256, 0, stream>>>(dst, deg);
  scan1_kernel<<<NPART, 256, 0, stream>>>(deg, excl, parts);
  scan2_kernel<<<1, 512, 0, stream>>>(parts);
  scan3_kernel<<<((N_NODES + 1) + 255) / 256, 256, 0, stream>>>(excl, parts, deg,
                                                                row_ptr, cursor, inv_deg);
  fill_kernel<<<EB, 256, 0, stream>>>(src, dst, cursor, ssrc);

  // ---- prep: split x; swizzle all 8 weights in one launch
  cast_split_kernel<<<(N_NODES * K_DIM / 4 + 255) / 256, 256, 0, stream>>>(x, Xh, Xl);
  swizzle_all_kernel<<<dim3(64, 1, 8), 256, 0, stream>>>(
      w_self0, w_neigh0, fc_w, fc2_w, w_self1, w_neigh1, w_self2, w_neigh2,
      ws0, wn0, wfc, wf2, ws1, wn1, ws2, wn2);

  // ---- network (plane ping-pong: X pair + B1 pair)
  const int AB = (N_NODES + 31) / 32;
  const int GB = (N_NODES + 127) / 128;

  // layer 0: agg(X)->B1 ; relu(X@Ws0 + B1@Wn0 + b) -> B1 (alias-safe)
  agg_kernel<<<AB, 256, 0, stream>>>(Xh, row_ptr, ssrc, inv_deg, B1h, B1l);
  mfma_gemm_kernel<128, true, true, true><<<GB, 256, 0, stream>>>(
      Xh, Xl, B1h, B1l, ws0, wn0, b_self0, B1h, B1l, nullptr);
  // NGNN fc layers: B1 -> X -> B1
  mfma_gemm_kernel<128, false, true, true><<<GB, 256, 0, stream>>>(
      B1h, B1l, B1h, B1l, wfc, wfc, fc_b, Xh, Xl, nullptr);
  mfma_gemm_kernel<128, false, true, true><<<GB, 256, 0, stream>>>(
      Xh, Xl, Xh, Xl, wf2, wf2, fc2_b, B1h, B1l, nullptr);
  // layer 1: agg(B1)->X ; relu(B1@Ws1 + X@Wn1 + b) -> B1
  agg_kernel<<<AB, 256, 0, stream>>>(B1h, row_ptr, ssrc, inv_deg, Xh, Xl);
  mfma_gemm_kernel<128, true, true, true><<<GB, 256, 0, stream>>>(
      B1h, B1l, Xh, Xl, ws1, wn1, b_self1, B1h, B1l, nullptr);
  // layer 2: agg(B1)->X ; B1@Ws2 + X@Wn2 + b -> d_out (fp32, DOUT=64)
  agg_kernel<<<AB, 256, 0, stream>>>(B1h, row_ptr, ssrc, inv_deg, Xh, Xl);
  mfma_gemm_kernel<64, true, false, false><<<GB, 256, 0, stream>>>(
      B1h, B1l, Xh, Xl, ws2, wn2, b_self2, nullptr, nullptr, (float*)d_out);
}

// Round 7
// 374.367 us; speedup vs baseline: 75.4854x; 1.2495x over previous
//
#include <hip/hip_runtime.h>

#define N_NODES 100000
#define N_EDGES 600000
#define K_DIM   128
#define NPART   ((N_NODES + 255) / 256)   // 391 scan blocks

typedef unsigned short ushort_t;
typedef short v8s __attribute__((ext_vector_type(8)));   // 8 bf16 = 4 VGPRs
typedef float v4f __attribute__((ext_vector_type(4)));   // MFMA acc frag

// fp32 -> bf16 round-to-nearest-even (inputs are finite; no NaN handling)
__device__ __forceinline__ ushort_t f2b(float f) {
  unsigned u = __builtin_bit_cast(unsigned, f);
  unsigned r = u + 0x7FFFu + ((u >> 16) & 1u);
  return (ushort_t)(r >> 16);
}
__device__ __forceinline__ float b2f(ushort_t h) {
  return __builtin_bit_cast(float, (unsigned)h << 16);
}
// unpack a uint holding two bf16 (little-endian: element0 = low half)
__device__ __forceinline__ float blo(unsigned u) {
  return __builtin_bit_cast(float, u << 16);
}
__device__ __forceinline__ float bhi(unsigned u) {
  return __builtin_bit_cast(float, u & 0xFFFF0000u);
}

// ---------------------------------------------------------------- CSR build

__global__ void deg_kernel(const int* __restrict__ dst, int* __restrict__ deg) {
  int e = blockIdx.x * blockDim.x + threadIdx.x;
  if (e < N_EDGES) atomicAdd(&deg[dst[e]], 1);
}

__global__ void scan1_kernel(const int* __restrict__ deg, int* __restrict__ excl,
                             int* __restrict__ partials) {
  __shared__ int s[256];
  int t = threadIdx.x, i = blockIdx.x * 256 + t;
  int v = (i < N_NODES) ? deg[i] : 0;
  s[t] = v;
  __syncthreads();
  for (int off = 1; off < 256; off <<= 1) {
    int x = (t >= off) ? s[t - off] : 0;
    __syncthreads();
    s[t] += x;
    __syncthreads();
  }
  if (i < N_NODES) excl[i] = s[t] - v;
  if (t == 255) partials[blockIdx.x] = s[t];
}

__global__ void scan2_kernel(int* __restrict__ partials) {
  __shared__ int s[512];
  int t = threadIdx.x;
  int v = (t < NPART) ? partials[t] : 0;
  s[t] = v;
  __syncthreads();
  for (int off = 1; off < 512; off <<= 1) {
    int x = (t >= off) ? s[t - off] : 0;
    __syncthreads();
    s[t] += x;
    __syncthreads();
  }
  if (t < NPART) partials[t] = s[t] - v;   // exclusive block offsets
}

__global__ void scan3_kernel(const int* __restrict__ excl, const int* __restrict__ partials,
                             const int* __restrict__ deg, int* __restrict__ row_ptr,
                             int* __restrict__ cursor, float* __restrict__ inv_deg) {
  int i = blockIdx.x * blockDim.x + threadIdx.x;
  if (i < N_NODES) {
    int rp = excl[i] + partials[i >> 8];
    row_ptr[i] = rp;
    cursor[i] = rp;
    inv_deg[i] = 1.0f / (float)(deg[i] > 1 ? deg[i] : 1);
  } else if (i == N_NODES) {
    row_ptr[N_NODES] = N_EDGES;
  }
}

__global__ void fill_kernel(const int* __restrict__ src, const int* __restrict__ dst,
                            int* __restrict__ cursor, int* __restrict__ ssrc) {
  int e = blockIdx.x * blockDim.x + threadIdx.x;
  if (e < N_EDGES) {
    int p = atomicAdd(&cursor[dst[e]], 1);
    ssrc[p] = src[e];
  }
}

// ---------------------------------------------------------------- prep

// x (fp32) -> bf16 plane (single plane; round-6 showed the precision slack)
__global__ void cast_kernel(const float* __restrict__ X, ushort_t* __restrict__ Xb) {
  int i = (blockIdx.x * 256 + threadIdx.x) * 4;
  if (i >= N_NODES * K_DIM) return;
  float4 v = *(const float4*)(X + i);
  ushort4 h;
  h.x = f2b(v.x); h.y = f2b(v.y); h.z = f2b(v.z); h.w = f2b(v.w);
  *(ushort4*)(Xb + i) = h;
}

// All 8 weights swizzled in ONE launch (blockIdx.z selects the weight).
// Layout: sw[(k>>3)*DOUT*8 + n*8 + (k&7)] -> lane's 8 k-values contiguous.
__global__ void swizzle_all_kernel(
    const float* __restrict__ w0, const float* __restrict__ w1,
    const float* __restrict__ w2, const float* __restrict__ w3,
    const float* __restrict__ w4, const float* __restrict__ w5,
    const float* __restrict__ w6, const float* __restrict__ w7,
    ushort_t* __restrict__ s0, ushort_t* __restrict__ s1,
    ushort_t* __restrict__ s2, ushort_t* __restrict__ s3,
    ushort_t* __restrict__ s4, ushort_t* __restrict__ s5,
    ushort_t* __restrict__ s6, ushort_t* __restrict__ s7) {
  const int z = blockIdx.z;
  const float* W;
  ushort_t* S;
  int dout = 128;
  switch (z) {
    case 0: W = w0; S = s0; break;
    case 1: W = w1; S = s1; break;
    case 2: W = w2; S = s2; break;
    case 3: W = w3; S = s3; break;
    case 4: W = w4; S = s4; break;
    case 5: W = w5; S = s5; break;
    case 6: W = w6; S = s6; dout = 64; break;
    default: W = w7; S = s7; dout = 64; break;
  }
  int t = blockIdx.x * 256 + threadIdx.x;
  if (t >= K_DIM * dout) return;
  int k = t / dout, n = t % dout;
  S[(k >> 3) * (dout * 8) + n * 8 + (k & 7)] = f2b(W[t]);
}

// ---------------------------------------------------------------- aggregate
// AGG[v] = inv_deg[v] * sum_{u->v} H[u]  (bf16 in, bf16 out -- single plane).
// 8 lanes/row (16 cols each), 32 rows/block, 2-edge unroll for MLP,
// max-occupancy launch bounds (VGPR 28 -> 8 waves/EU fits).

__global__ __launch_bounds__(256, 8) void agg_kernel(
    const ushort_t* __restrict__ Hh,
    const int* __restrict__ row_ptr, const int* __restrict__ ssrc,
    const float* __restrict__ inv_deg, ushort_t* __restrict__ Ah) {
  const int tid = threadIdx.x;
  const int c0  = (tid & 7) * 16;   // 16 columns per lane
  const int r   = tid >> 3;
  const int v   = blockIdx.x * 32 + r;
  if (v >= N_NODES) return;

  float a[16];
  #pragma unroll
  for (int i = 0; i < 16; ++i) a[i] = 0.f;

  const int beg = row_ptr[v], end = row_ptr[v + 1];
  int e = beg;
  for (; e + 2 <= end; e += 2) {
    const size_t r0 = (size_t)ssrc[e] * K_DIM + c0;
    const size_t r1 = (size_t)ssrc[e + 1] * K_DIM + c0;
    const uint4 p0 = *(const uint4*)(Hh + r0);
    const uint4 p1 = *(const uint4*)(Hh + r0 + 8);
    const uint4 q0 = *(const uint4*)(Hh + r1);
    const uint4 q1 = *(const uint4*)(Hh + r1 + 8);
    a[ 0] += blo(p0.x) + blo(q0.x);  a[ 1] += bhi(p0.x) + bhi(q0.x);
    a[ 2] += blo(p0.y) + blo(q0.y);  a[ 3] += bhi(p0.y) + bhi(q0.y);
    a[ 4] += blo(p0.z) + blo(q0.z);  a[ 5] += bhi(p0.z) + bhi(q0.z);
    a[ 6] += blo(p0.w) + blo(q0.w);  a[ 7] += bhi(p0.w) + bhi(q0.w);
    a[ 8] += blo(p1.x) + blo(q1.x);  a[ 9] += bhi(p1.x) + bhi(q1.x);
    a[10] += blo(p1.y) + blo(q1.y);  a[11] += bhi(p1.y) + bhi(q1.y);
    a[12] += blo(p1.z) + blo(q1.z);  a[13] += bhi(p1.z) + bhi(q1.z);
    a[14] += blo(p1.w) + blo(q1.w);  a[15] += bhi(p1.w) + bhi(q1.w);
  }
  if (e < end) {
    const size_t r0 = (size_t)ssrc[e] * K_DIM + c0;
    const uint4 p0 = *(const uint4*)(Hh + r0);
    const uint4 p1 = *(const uint4*)(Hh + r0 + 8);
    a[ 0] += blo(p0.x);  a[ 1] += bhi(p0.x);
    a[ 2] += blo(p0.y);  a[ 3] += bhi(p0.y);
    a[ 4] += blo(p0.z);  a[ 5] += bhi(p0.z);
    a[ 6] += blo(p0.w);  a[ 7] += bhi(p0.w);
    a[ 8] += blo(p1.x);  a[ 9] += bhi(p1.x);
    a[10] += blo(p1.y);  a[11] += bhi(p1.y);
    a[12] += blo(p1.z);  a[13] += bhi(p1.z);
    a[14] += blo(p1.w);  a[15] += bhi(p1.w);
  }
  const float sc = inv_deg[v];
  const size_t wo = (size_t)v * K_DIM + c0;
  #pragma unroll
  for (int g = 0; g < 4; ++g) {
    ushort4 oh;
    oh.x = f2b(a[4 * g + 0] * sc);
    oh.y = f2b(a[4 * g + 1] * sc);
    oh.z = f2b(a[4 * g + 2] * sc);
    oh.w = f2b(a[4 * g + 3] * sc);
    *(ushort4*)(Ah + wo + 4 * g) = oh;
  }
}

// ---------------------------------------------------------------- MFMA GEMM
// out = act( A1@W1 [+ A2@W2] + b ), bf16 activations, 16x16x32 bf16 MFMA.
// N-SPLIT: each block computes 128 rows x 64 cols (col0 = blockIdx.y*64) ->
// 2x grid for DOUT=128 (round-6 counters: gemm was latency-bound at 3
// blocks/CU grid cap, MfmaUtil 7%, VALUBusy 8%). 16 KB weight LDS.
// NO output/input aliasing allowed under n-split (a col-half block writes
// rows another col-half block still reads) -- launcher rotates X/Y/Z planes.
// Loop shape preserved from round 5 (known-good allocation). DO NOT unroll
// outer loops / prefetch into registers (rounds 2-3: catastrophic spills;
// tripwire = WRITE_SIZE >> output bytes).

template <int DOUT_FULL, bool TWO, bool RELU, bool BF16_OUT>
__global__ __launch_bounds__(256, 4) void mfma_gemm_kernel(
    const ushort_t* __restrict__ A1, const ushort_t* __restrict__ A2,
    const ushort_t* __restrict__ W1sw, const ushort_t* __restrict__ W2sw,
    const float* __restrict__ bias,
    ushort_t* __restrict__ Obf, float* __restrict__ Ofp) {
  constexpr int COLT = 64;           // cols per block
  constexpr int NT   = COLT / 16;    // 4 n-tiles per wave
  constexpr int SWN  = (K_DIM / 8) * COLT * 8;   // 8192 ushorts = 16 KB
  __shared__ ushort_t sW[SWN];

  const int tid  = threadIdx.x;
  const int wv   = tid >> 6;
  const int lane = tid & 63;
  const int lm   = lane & 15;    // m (A) / n (B) index within tile
  const int q    = lane >> 4;    // quad: k-group for A/B, row-group for C
  const int row0 = blockIdx.x * 128 + wv * 32;
  const int col0 = blockIdx.y * COLT;

  // stage W1 column-slice: local [kg][nl][8] <- global [kg][col0+nl][8]
  for (int i = tid * 8; i < SWN; i += 2048) {
    const int kg = i / (COLT * 8);
    const int nl = (i >> 3) & (COLT - 1);
    *(uint4*)&sW[i] = *(const uint4*)&W1sw[kg * (DOUT_FULL * 8) + (col0 + nl) * 8];
  }
  __syncthreads();

  int ra = row0 + lm;       ra = ra < N_NODES ? ra : N_NODES - 1;
  int rb = row0 + 16 + lm;  rb = rb < N_NODES ? rb : N_NODES - 1;
  const size_t off0 = (size_t)ra * K_DIM;
  const size_t off1 = (size_t)rb * K_DIM;

  v4f acc[2][NT];
  #pragma unroll
  for (int m = 0; m < 2; ++m)
    #pragma unroll
    for (int n = 0; n < NT; ++n) acc[m][n] = (v4f){0.f, 0.f, 0.f, 0.f};

  // ---- phase 1: A1 @ W1
  for (int ks = 0; ks < K_DIM / 32; ++ks) {
    const int ko = ks * 32 + q * 8;
    const v8s a0 = *(const v8s*)(A1 + off0 + ko);
    const v8s a1 = *(const v8s*)(A1 + off1 + ko);
    #pragma unroll
    for (int nt = 0; nt < NT; ++nt) {
      const v8s b = *(const v8s*)&sW[((ks * 4 + q) * COLT + nt * 16 + lm) * 8];
      acc[0][nt] = __builtin_amdgcn_mfma_f32_16x16x32_bf16(a0, b, acc[0][nt], 0, 0, 0);
      acc[1][nt] = __builtin_amdgcn_mfma_f32_16x16x32_bf16(a1, b, acc[1][nt], 0, 0, 0);
    }
  }

  if (TWO) {
    __syncthreads();
    for (int i = tid * 8; i < SWN; i += 2048) {
      const int kg = i / (COLT * 8);
      const int nl = (i >> 3) & (COLT - 1);
      *(uint4*)&sW[i] = *(const uint4*)&W2sw[kg * (DOUT_FULL * 8) + (col0 + nl) * 8];
    }
    __syncthreads();

    // ---- phase 2: A2 @ W2
    for (int ks = 0; ks < K_DIM / 32; ++ks) {
      const int ko = ks * 32 + q * 8;
      const v8s a0 = *(const v8s*)(A2 + off0 + ko);
      const v8s a1 = *(const v8s*)(A2 + off1 + ko);
      #pragma unroll
      for (int nt = 0; nt < NT; ++nt) {
        const v8s b = *(const v8s*)&sW[((ks * 4 + q) * COLT + nt * 16 + lm) * 8];
        acc[0][nt] = __builtin_amdgcn_mfma_f32_16x16x32_bf16(a0, b, acc[0][nt], 0, 0, 0);
        acc[1][nt] = __builtin_amdgcn_mfma_f32_16x16x32_bf16(a1, b, acc[1][nt], 0, 0, 0);
      }
    }
  }

  // ---- epilogue: C/D layout col=lane&15, row=quad*4+reg
  #pragma unroll
  for (int m = 0; m < 2; ++m) {
    #pragma unroll
    for (int nt = 0; nt < NT; ++nt) {
      const int col = col0 + nt * 16 + lm;
      const float bv = bias[col];
      #pragma unroll
      for (int r = 0; r < 4; ++r) {
        const int row = row0 + m * 16 + q * 4 + r;
        if (row < N_NODES) {
          float v = acc[m][nt][r] + bv;
          if (RELU) v = v > 0.f ? v : 0.f;
          if (BF16_OUT) Obf[(size_t)row * DOUT_FULL + col] = f2b(v);
          else          Ofp[(size_t)row * DOUT_FULL + col] = v;
        }
      }
    }
  }
}

// ---------------------------------------------------------------- launcher

extern "C" void kernel_launch(void* const* d_in, const int* in_sizes, int n_in,
                              void* d_out, int out_size, void* d_ws, size_t ws_size,
                              hipStream_t stream) {
  const float* x        = (const float*)d_in[0];
  const int*   src      = (const int*)d_in[1];
  const int*   dst      = (const int*)d_in[2];
  const float* w_self0  = (const float*)d_in[3];
  const float* b_self0  = (const float*)d_in[4];
  const float* w_neigh0 = (const float*)d_in[5];
  const float* fc_w     = (const float*)d_in[6];
  const float* fc_b     = (const float*)d_in[7];
  const float* fc2_w    = (const float*)d_in[8];
  const float* fc2_b    = (const float*)d_in[9];
  const float* w_self1  = (const float*)d_in[10];
  const float* b_self1  = (const float*)d_in[11];
  const float* w_neigh1 = (const float*)d_in[12];
  const float* w_self2  = (const float*)d_in[13];
  const float* b_self2  = (const float*)d_in[14];
  const float* w_neigh2 = (const float*)d_in[15];

  char* p = (char*)d_ws;
  auto carve = [&](size_t bytes) {
    void* q = (void*)p;
    p += (bytes + 511) & ~(size_t)511;
    return q;
  };
  const size_t PLANE = (size_t)N_NODES * K_DIM * sizeof(ushort_t);   // 25.6 MB
  ushort_t* X   = (ushort_t*)carve(PLANE);
  ushort_t* Y   = (ushort_t*)carve(PLANE);
  ushort_t* Z   = (ushort_t*)carve(PLANE);
  ushort_t* ws0 = (ushort_t*)carve(K_DIM * 128 * 2);
  ushort_t* wn0 = (ushort_t*)carve(K_DIM * 128 * 2);
  ushort_t* wfc = (ushort_t*)carve(K_DIM * 128 * 2);
  ushort_t* wf2 = (ushort_t*)carve(K_DIM * 128 * 2);
  ushort_t* ws1 = (ushort_t*)carve(K_DIM * 128 * 2);
  ushort_t* wn1 = (ushort_t*)carve(K_DIM * 128 * 2);
  ushort_t* ws2 = (ushort_t*)carve(K_DIM * 64 * 2);
  ushort_t* wn2 = (ushort_t*)carve(K_DIM * 64 * 2);
  int*   ssrc    = (int*)carve((size_t)N_EDGES * 4);
  int*   row_ptr = (int*)carve((size_t)(N_NODES + 1) * 4);
  int*   cursor  = (int*)carve((size_t)N_NODES * 4);
  int*   deg     = (int*)carve((size_t)N_NODES * 4);
  int*   excl    = (int*)carve((size_t)N_NODES * 4);
  int*   parts   = (int*)carve(512 * 4);
  float* inv_deg = (float*)carve((size_t)N_NODES * 4);

  // ---- CSR build (by dst)
  hipMemsetAsync(deg, 0, (size_t)N_NODES * 4, stream);
  const int EB = (N_EDGES + 255) / 256;
  deg_kernel<<<EB, 256, 0, stream>>>(dst, deg);
  scan1_kernel<<<NPART, 256, 0, stream>>>(deg, excl, parts);
  scan2_kernel<<<1, 512, 0, stream>>>(parts);
  scan3_kernel<<<((N_NODES + 1) + 255) / 256, 256, 0, stream>>>(excl, parts, deg,
                                                                row_ptr, cursor, inv_deg);
  fill_kernel<<<EB, 256, 0, stream>>>(src, dst, cursor, ssrc);

  // ---- prep: cast x to bf16; swizzle all 8 weights in one launch
  cast_kernel<<<(N_NODES * K_DIM / 4 + 255) / 256, 256, 0, stream>>>(x, X);
  swizzle_all_kernel<<<dim3(64, 1, 8), 256, 0, stream>>>(
      w_self0, w_neigh0, fc_w, fc2_w, w_self1, w_neigh1, w_self2, w_neigh2,
      ws0, wn0, wfc, wf2, ws1, wn1, ws2, wn2);

  // ---- network: strict no-alias rotation over X/Y/Z (n-split requirement)
  const int AB = (N_NODES + 31) / 32;
  const int GB = (N_NODES + 127) / 128;
  const dim3 G2(GB, 2), G1(GB, 1);

  // layer 0: agg(X)->Y ; relu(X@Ws0 + Y@Wn0 + b) -> Z
  agg_kernel<<<AB, 256, 0, stream>>>(X, row_ptr, ssrc, inv_deg, Y);
  mfma_gemm_kernel<128, true, true, true><<<G2, 256, 0, stream>>>(
      X, Y, ws0, wn0, b_self0, Z, nullptr);
  // NGNN fc layers: Z -> X -> Y
  mfma_gemm_kernel<128, false, true, true><<<G2, 256, 0, stream>>>(
      Z, nullptr, wfc, nullptr, fc_b, X, nullptr);
  mfma_gemm_kernel<128, false, true, true><<<G2, 256, 0, stream>>>(
      X, nullptr, wf2, nullptr, fc2_b, Y, nullptr);
  // layer 1: agg(Y)->X ; relu(Y@Ws1 + X@Wn1 + b) -> Z
  agg_kernel<<<AB, 256, 0, stream>>>(Y, row_ptr, ssrc, inv_deg, X);
  mfma_gemm_kernel<128, true, true, true><<<G2, 256, 0, stream>>>(
      Y, X, ws1, wn1, b_self1, Z, nullptr);
  // layer 2: agg(Z)->Y ; Z@Ws2 + Y@Wn2 + b -> d_out (fp32, DOUT=64)
  agg_kernel<<<AB, 256, 0, stream>>>(Z, row_ptr, ssrc, inv_deg, Y);
  mfma_gemm_kernel<64, true, false, false><<<G1, 256, 0, stream>>>(
      Z, Y, ws2, wn2, b_self2, nullptr, (float*)d_out);
}